// Round 2
// baseline (136.051 us; speedup 1.0000x reference)
//
#include <hip/hip_runtime.h>

// Problem geometry: input/target are (1, 3, 96, 256, 256) float32, contiguous.
// Each channel is a contiguous block of 96*256*256 = 6,291,456 floats
// = 1,572,864 float4. Grid: 1024 blocks/channel x 256 threads
// -> exactly 6 float4 per array per thread (compile-time trip count).
#define NCH 3
#define PER_CH4 1572864
#define BLOCKS_PER_CH 1024
#define THREADS 256
#define ITERS 6            // PER_CH4 / (BLOCKS_PER_CH*THREADS) == 6 exactly
#define STRIDE (BLOCKS_PER_CH * THREADS)
#define EPS 1e-6f

// acc layout in d_ws: acc[ch*3 + 0] = sum(x*t), +1 = sum(x*x), +2 = sum(t*t)
__global__ void __launch_bounds__(256)
dice_reduce_kernel(const float4* __restrict__ x, const float4* __restrict__ t,
                   float* __restrict__ acc) {
    const int ch = blockIdx.y;
    const size_t base = (size_t)ch * PER_CH4 + blockIdx.x * THREADS + threadIdx.x;

    // Phase 1: issue all 12 loads before any use (hide HBM latency with MLP).
    float4 xv[ITERS], tv[ITERS];
#pragma unroll
    for (int k = 0; k < ITERS; ++k) {
        xv[k] = x[base + (size_t)k * STRIDE];
        tv[k] = t[base + (size_t)k * STRIDE];
    }

    // Phase 2: accumulate.
    float sxt = 0.f, sxx = 0.f, stt = 0.f;
#pragma unroll
    for (int k = 0; k < ITERS; ++k) {
        sxt += xv[k].x * tv[k].x + xv[k].y * tv[k].y + xv[k].z * tv[k].z + xv[k].w * tv[k].w;
        sxx += xv[k].x * xv[k].x + xv[k].y * xv[k].y + xv[k].z * xv[k].z + xv[k].w * xv[k].w;
        stt += tv[k].x * tv[k].x + tv[k].y * tv[k].y + tv[k].z * tv[k].z + tv[k].w * tv[k].w;
    }

    // Wave-64 reduction
    for (int off = 32; off > 0; off >>= 1) {
        sxt += __shfl_down(sxt, off, 64);
        sxx += __shfl_down(sxx, off, 64);
        stt += __shfl_down(stt, off, 64);
    }

    // Cross-wave reduction via LDS (256 threads = 4 waves)
    __shared__ float lds[3][4];
    const int lane = threadIdx.x & 63;
    const int wave = threadIdx.x >> 6;
    if (lane == 0) {
        lds[0][wave] = sxt;
        lds[1][wave] = sxx;
        lds[2][wave] = stt;
    }
    __syncthreads();
    if (threadIdx.x == 0) {
        float bxt = lds[0][0] + lds[0][1] + lds[0][2] + lds[0][3];
        float bxx = lds[1][0] + lds[1][1] + lds[1][2] + lds[1][3];
        float btt = lds[2][0] + lds[2][1] + lds[2][2] + lds[2][3];
        atomicAdd(&acc[ch * 3 + 0], bxt);
        atomicAdd(&acc[ch * 3 + 1], bxx);
        atomicAdd(&acc[ch * 3 + 2], btt);
    }
}

__global__ void dice_finalize_kernel(const float* __restrict__ acc,
                                     float* __restrict__ out) {
    if (threadIdx.x == 0 && blockIdx.x == 0) {
        float loss = 0.f;
        for (int c = 0; c < NCH; ++c) {
            float num = acc[c * 3 + 0];
            float den = acc[c * 3 + 1] + acc[c * 3 + 2];
            loss += -2.f * (num / fmaxf(den, EPS));
        }
        out[0] = loss;
    }
}

extern "C" void kernel_launch(void* const* d_in, const int* in_sizes, int n_in,
                              void* d_out, int out_size, void* d_ws, size_t ws_size,
                              hipStream_t stream) {
    const float4* x = (const float4*)d_in[0];
    const float4* t = (const float4*)d_in[1];
    float* acc = (float*)d_ws;
    float* out = (float*)d_out;

    // Workspace is poisoned (0xAA) and never re-poisoned between replays:
    // zero the 9 accumulators every call.
    hipMemsetAsync(acc, 0, NCH * 3 * sizeof(float), stream);

    dim3 grid(BLOCKS_PER_CH, NCH);
    dice_reduce_kernel<<<grid, THREADS, 0, stream>>>(x, t, acc);
    dice_finalize_kernel<<<1, 64, 0, stream>>>(acc, out);
}

// Round 3
// 85.098 us; speedup vs baseline: 1.5988x; 1.5988x over previous
//
#include <hip/hip_runtime.h>

// Problem: channelwise Sorensen-Dice over (1,3,96,256,256) fp32.
// Each channel = contiguous 6,291,456 floats. Need per-channel
// sum(x*t), sum(x*x), sum(t*t); then loss = sum_c -2*num/max(den,eps).
//
// Strategy: latency-bound fix. global_load_lds (16B/lane, 1KB/wave/instr)
// keeps outstanding bytes off the VGPR file; each wave stages a private
// 2KB+2KB chunk into its own LDS slice (no barrier needed), waits vmcnt(0),
// reduces from LDS. ~24 waves/CU x 4KB in flight >> latency-BW product.
#define NCH 3
#define PER_CH 6291456
#define THREADS 256
#define WPB 4                       // waves per block
#define GRIDX 512                   // blocks per channel
#define NWX (GRIDX * WPB)           // 2048 waves per channel
#define CHUNK 512                   // floats per array per chunk (2 KB)
#define CHUNKS_PER_WAVE 6           // PER_CH / CHUNK / NWX == 6 exactly
#define EPS 1e-6f

__device__ __forceinline__ void gload16(const float* g, float* l) {
    // dwordx4 direct global->LDS: lane i's 16B land at l + i*16.
    __builtin_amdgcn_global_load_lds(
        (__attribute__((address_space(1))) void*)g,
        (__attribute__((address_space(3))) void*)l,
        16, 0, 0);
}

// acc layout in d_ws: acc[ch*3 + 0] = sum(x*t), +1 = sum(x*x), +2 = sum(t*t)
__global__ void __launch_bounds__(256)
dice_reduce_kernel(const float* __restrict__ x, const float* __restrict__ t,
                   float* __restrict__ acc) {
    __shared__ __align__(16) float lx[WPB][CHUNK];
    __shared__ __align__(16) float lt[WPB][CHUNK];
    __shared__ float red[3][WPB];

    const int lane = threadIdx.x & 63;
    const int wave = threadIdx.x >> 6;
    const int ch = blockIdx.y;
    const int gwx = blockIdx.x * WPB + wave;
    const size_t ch_base = (size_t)ch * PER_CH;

    float* lxw = &lx[wave][0];
    float* ltw = &lt[wave][0];

    float sxt = 0.f, sxx = 0.f, stt = 0.f;

#pragma unroll 1
    for (int j = 0; j < CHUNKS_PER_WAVE; ++j) {
        const size_t gbase = ch_base + (size_t)(gwx + j * NWX) * CHUNK;
        const float* gx = x + gbase + lane * 4;   // lane*16 bytes
        const float* gt = t + gbase + lane * 4;
        gload16(gx,       lxw);         // floats [0,256)
        gload16(gx + 256, lxw + 256);   // floats [256,512)
        gload16(gt,       ltw);
        gload16(gt + 256, ltw + 256);
        asm volatile("s_waitcnt vmcnt(0)" ::: "memory");

        float4 x0 = *reinterpret_cast<const float4*>(lxw + lane * 4);
        float4 x1 = *reinterpret_cast<const float4*>(lxw + 256 + lane * 4);
        float4 t0 = *reinterpret_cast<const float4*>(ltw + lane * 4);
        float4 t1 = *reinterpret_cast<const float4*>(ltw + 256 + lane * 4);

        sxt += x0.x * t0.x + x0.y * t0.y + x0.z * t0.z + x0.w * t0.w
             + x1.x * t1.x + x1.y * t1.y + x1.z * t1.z + x1.w * t1.w;
        sxx += x0.x * x0.x + x0.y * x0.y + x0.z * x0.z + x0.w * x0.w
             + x1.x * x1.x + x1.y * x1.y + x1.z * x1.z + x1.w * x1.w;
        stt += t0.x * t0.x + t0.y * t0.y + t0.z * t0.z + t0.w * t0.w
             + t1.x * t1.x + t1.y * t1.y + t1.z * t1.z + t1.w * t1.w;
    }

    // Wave-64 reduction
    for (int off = 32; off > 0; off >>= 1) {
        sxt += __shfl_down(sxt, off, 64);
        sxx += __shfl_down(sxx, off, 64);
        stt += __shfl_down(stt, off, 64);
    }

    // Cross-wave reduction (4 waves) + one atomic per block per sum
    if (lane == 0) {
        red[0][wave] = sxt;
        red[1][wave] = sxx;
        red[2][wave] = stt;
    }
    __syncthreads();
    if (threadIdx.x == 0) {
        float bxt = red[0][0] + red[0][1] + red[0][2] + red[0][3];
        float bxx = red[1][0] + red[1][1] + red[1][2] + red[1][3];
        float btt = red[2][0] + red[2][1] + red[2][2] + red[2][3];
        atomicAdd(&acc[ch * 3 + 0], bxt);
        atomicAdd(&acc[ch * 3 + 1], bxx);
        atomicAdd(&acc[ch * 3 + 2], btt);
    }
}

__global__ void dice_finalize_kernel(const float* __restrict__ acc,
                                     float* __restrict__ out) {
    if (threadIdx.x == 0 && blockIdx.x == 0) {
        float loss = 0.f;
        for (int c = 0; c < NCH; ++c) {
            float num = acc[c * 3 + 0];
            float den = acc[c * 3 + 1] + acc[c * 3 + 2];
            loss += -2.f * (num / fmaxf(den, EPS));
        }
        out[0] = loss;
    }
}

extern "C" void kernel_launch(void* const* d_in, const int* in_sizes, int n_in,
                              void* d_out, int out_size, void* d_ws, size_t ws_size,
                              hipStream_t stream) {
    const float* x = (const float*)d_in[0];
    const float* t = (const float*)d_in[1];
    float* acc = (float*)d_ws;
    float* out = (float*)d_out;

    // Workspace is poisoned (0xAA) and never re-poisoned between replays:
    // zero the 9 accumulators every call.
    hipMemsetAsync(acc, 0, NCH * 3 * sizeof(float), stream);

    dim3 grid(GRIDX, NCH);
    dice_reduce_kernel<<<grid, THREADS, 0, stream>>>(x, t, acc);
    dice_finalize_kernel<<<1, 64, 0, stream>>>(acc, out);
}